// Round 7
// baseline (859.798 us; speedup 1.0000x reference)
//
#include <hip/hip_runtime.h>
#include <hip/hip_bf16.h>
#include <stdint.h>

// Problem constants: B=4, S=2048, IN=4096, OUT=11008
#define M_DIM 8192   // B*S
#define N_DIM 11008  // OUT
#define K_DIM 4096   // IN
#define NGROUP 32    // K_DIM/128

#define BM 256
#define BN 128
#define BK 64
#define NT (K_DIM / BK)  // 64 K-tiles

typedef __attribute__((ext_vector_type(4))) float f32x4;
typedef __attribute__((ext_vector_type(8))) short short8;
typedef __attribute__((ext_vector_type(8))) __bf16 bf16x8;

static_assert(M_DIM % BM == 0 && N_DIM % BN == 0 && K_DIM % BK == 0, "tiling");

__device__ __forceinline__ unsigned short f2bf(float f) {
  union { float f; unsigned int u; } v; v.f = f;
  unsigned int r = v.u + 0x7FFFu + ((v.u >> 16) & 1u);  // RNE
  return (unsigned short)(r >> 16);
}

// ---------- prepass 1: x fp32 -> bf16 ----------
__global__ __launch_bounds__(256) void cvt_x_kernel(const float* __restrict__ x,
                                                    unsigned short* __restrict__ xb) {
  size_t i = ((size_t)blockIdx.x * 256 + threadIdx.x) * 8;
  float4 a = *(const float4*)(x + i);
  float4 b = *(const float4*)(x + i + 4);
  short8 o;
  o[0] = (short)f2bf(a.x); o[1] = (short)f2bf(a.y);
  o[2] = (short)f2bf(a.z); o[3] = (short)f2bf(a.w);
  o[4] = (short)f2bf(b.x); o[5] = (short)f2bf(b.y);
  o[6] = (short)f2bf(b.z); o[7] = (short)f2bf(b.w);
  *(short8*)(xb + i) = o;
}

// ---------- prepass 2: dequant packed int4 -> bf16 W[N][K] ----------
__global__ __launch_bounds__(256) void dequant_kernel(const int* __restrict__ qw,
                                                      const float* __restrict__ sc,
                                                      const float* __restrict__ zp,
                                                      unsigned short* __restrict__ W) {
  size_t chunk = (size_t)blockIdx.x * 256 + threadIdx.x;  // 4 packed int32 = 8 weights
  int row = (int)(chunk >> 9);
  int c4  = (int)(chunk & 511);
  int g   = c4 >> 4;
  float s = sc[row * NGROUP + g];
  float z = zp[row * NGROUP + g];
  int4 q = *(const int4*)(qw + (size_t)row * 2048 + c4 * 4);
  int qq[4] = {q.x, q.y, q.z, q.w};
  short8 o;
#pragma unroll
  for (int t = 0; t < 4; ++t) {
    o[2 * t]     = (short)f2bf(((float)(qq[t] & 15)        - z) * s);
    o[2 * t + 1] = (short)f2bf(((float)((qq[t] >> 4) & 15) - z) * s);
  }
  *(short8*)(W + (size_t)row * K_DIM + (size_t)c4 * 8) = o;
}

// ---------- 256x128 GEMM, 2 k-half phases per K-tile (16x16x32 MFMA) ----------
__device__ __forceinline__ void gload_lds16(const void* g, void* l) {
  __builtin_amdgcn_global_load_lds((__attribute__((address_space(1))) void*)g,
                                   (__attribute__((address_space(3))) void*)l,
                                   16, 0, 0);
}

// Stage A k-half panel [256 rows][32 cols] (16KB), 2 loads/thread.
__device__ __forceinline__ void stage2(const unsigned short* s0,
                                       const unsigned short* s1,
                                       unsigned short* panel, int wave, int koff) {
  gload_lds16(s0 + koff, panel + wave * 512);
  gload_lds16(s1 + koff, panel + 4096 + wave * 512);
}
// Stage B k-half panel [128 rows][32 cols] (8KB), 1 load/thread.
__device__ __forceinline__ void stage1(const unsigned short* s0,
                                       unsigned short* panel, int wave, int koff) {
  gload_lds16(s0 + koff, panel + wave * 512);
}

#define VMC(N) asm volatile("s_waitcnt vmcnt(" #N ")" ::: "memory")

// One phase = one k-half: 8 ds_read_b128 (4 av + 4 bv), optional 3-load stage,
// barrier, 16 MFMA, counted vmcnt, barrier.  (R5's verified-good granularity.)
#define PHASEK(PA, PB, STAGE_STMT, VM_STMT)                                         \
  {                                                                                 \
    bf16x8 av[4], bv[4];                                                            \
    _Pragma("unroll") for (int m_ = 0; m_ < 4; ++m_)                                \
      av[m_] = *(const bf16x8*)&(PA)[abase + m_ * 512];                             \
    _Pragma("unroll") for (int n_ = 0; n_ < 4; ++n_)                                \
      bv[n_] = *(const bf16x8*)&(PB)[bbase + n_ * 512];                             \
    STAGE_STMT;                                                                     \
    __builtin_amdgcn_s_barrier();                                                   \
    __builtin_amdgcn_s_setprio(1);                                                  \
    _Pragma("unroll") for (int m_ = 0; m_ < 4; ++m_)                                \
      _Pragma("unroll") for (int n_ = 0; n_ < 4; ++n_)                              \
        acc[m_][n_] =                                                               \
            __builtin_amdgcn_mfma_f32_16x16x32_bf16(av[m_], bv[n_],                 \
                                                    acc[m_][n_], 0, 0, 0);          \
    __builtin_amdgcn_s_setprio(0);                                                  \
    VM_STMT;                                                                        \
    __builtin_amdgcn_s_barrier();                                                   \
  }

__global__ __launch_bounds__(512, 2) void gemm_8phase_kernel(const unsigned short* __restrict__ A,
                                                             const unsigned short* __restrict__ B,
                                                             float* __restrict__ C) {
  extern __shared__ unsigned short lds[];
  unsigned short* As = lds;            // [2 buf][2 kh][256*32] = 64KB
  unsigned short* Bs = lds + 32768;    // [2 buf][2 kh][128*32] = 32KB

  const int tid  = threadIdx.x;
  const int wave = tid >> 6;
  const int lane = tid & 63;
  const int wm = wave >> 1;   // 0..3 -> 64-row slab
  const int wn = wave & 1;    // 0..1 -> 64-col slab
  const int fr = lane & 15;
  const int cp = (lane >> 4) ^ ((fr >> 1) & 3);  // swizzled physical 16B-block (0-conflict)

  // XCD-chunked block swizzle (2752 = 8*344, bijective), bm-major mapping
  const int wg  = blockIdx.x;
  const int sz_ = (wg & 7) * 344 + (wg >> 3);
  const int bm = sz_ / 86;
  const int bn = sz_ % 86;
  const size_t row0 = (size_t)bm * BM;
  const size_t col0 = (size_t)bn * BN;

  const unsigned short* Ab = A + row0 * K_DIM;
  const unsigned short* Bb = B + col0 * K_DIM;

  // precomputed per-lane staging sources (swizzle baked into global col, rule #21)
  const int cl = (tid & 3) ^ ((tid >> 3) & 3);
  const int r0 = tid >> 2;
  const unsigned short* asrc0 = Ab + (size_t)r0 * K_DIM + cl * 8;
  const unsigned short* asrc1 = Ab + (size_t)(r0 + 128) * K_DIM + cl * 8;
  const unsigned short* bsrc0 = Bb + (size_t)r0 * K_DIM + cl * 8;   // B has 128 rows

  // fragment LDS element offsets (panel-local); frag mi at abase + mi*512
  const int abase = (wm * 64 + fr) * 32 + cp * 8;
  const int bbase = (wn * 64 + fr) * 32 + cp * 8;

  f32x4 acc[4][4];
#pragma unroll
  for (int i = 0; i < 4; ++i)
#pragma unroll
    for (int j = 0; j < 4; ++j) acc[i][j] = (f32x4){0.f, 0.f, 0.f, 0.f};

  // ---- prologue: stage tile 0 (kh0 group: 3 loads, kh1 group: 3 loads) ----
  stage2(asrc0, asrc1, As + 0 * 8192, wave, 0);
  stage1(bsrc0, Bs + 0 * 4096, wave, 0);
  stage2(asrc0, asrc1, As + 1 * 8192, wave, 32);
  stage1(bsrc0, Bs + 1 * 4096, wave, 32);
  VMC(3);                       // kh0 group landed; kh1 may be in flight
  __builtin_amdgcn_s_barrier();

  // ---- main loop: 2 phases per K-tile, one 3-load k-half group prefetch per phase ----
  for (int T = 0; T < NT - 1; ++T) {
    const int buf = T & 1, nb = buf ^ 1;
    unsigned short* A0 = As + (buf * 2 + 0) * 8192;
    unsigned short* A1 = As + (buf * 2 + 1) * 8192;
    unsigned short* B0 = Bs + (buf * 2 + 0) * 4096;
    unsigned short* B1 = Bs + (buf * 2 + 1) * 4096;
    unsigned short* nA0 = As + (nb * 2 + 0) * 8192;
    unsigned short* nA1 = As + (nb * 2 + 1) * 8192;
    unsigned short* nB0 = Bs + (nb * 2 + 0) * 4096;
    unsigned short* nB1 = Bs + (nb * 2 + 1) * 4096;
    const int k1 = (T + 1) * 64;      // prefetch col offset (elems)

    // ph1: compute kh0; stage (T+1).kh0 group; VMC(3) retires T.kh1 group
    PHASEK(A0, B0,
           { stage2(asrc0, asrc1, nA0, wave, k1); stage1(bsrc0, nB0, wave, k1); },
           VMC(3));
    // ph2: compute kh1; stage (T+1).kh1 group; VMC(3) retires (T+1).kh0 group
    PHASEK(A1, B1,
           { stage2(asrc0, asrc1, nA1, wave, k1 + 32); stage1(bsrc0, nB1, wave, k1 + 32); },
           VMC(3));
  }
  // ---- last tile: no prefetch; drain kh1 group before ph2 ----
  {
    const int buf = (NT - 1) & 1;
    unsigned short* A0 = As + (buf * 2 + 0) * 8192;
    unsigned short* A1 = As + (buf * 2 + 1) * 8192;
    unsigned short* B0 = Bs + (buf * 2 + 0) * 4096;
    unsigned short* B1 = Bs + (buf * 2 + 1) * 4096;
    PHASEK(A0, B0, , VMC(0));
    PHASEK(A1, B1, , );
  }

  // ---- epilogue: C/D layout col = lane&15, row = (lane>>4)*4 + v ----
  const int orow = (lane >> 4) * 4;
#pragma unroll
  for (int mi = 0; mi < 4; ++mi) {
#pragma unroll
    for (int n = 0; n < 4; ++n) {
      const size_t r = row0 + wm * 64 + mi * 16 + orow;
      const size_t c = col0 + wn * 64 + n * 16 + fr;
#pragma unroll
      for (int v = 0; v < 4; ++v)
        C[(r + v) * N_DIM + c] = acc[mi][n][v];
    }
  }
}

// ---------- fallback (only if d_ws too small): naive fused ----------
__global__ __launch_bounds__(256) void fallback_kernel(const float* __restrict__ x,
                                                       const int* __restrict__ qw,
                                                       const float* __restrict__ sc,
                                                       const float* __restrict__ zp,
                                                       float* __restrict__ out) {
  __shared__ float xs[K_DIM];
  const int m = blockIdx.y;
  const int n = blockIdx.x * 256 + threadIdx.x;
  for (int i = threadIdx.x; i < K_DIM; i += 256) xs[i] = x[(size_t)m * K_DIM + i];
  __syncthreads();
  float acc = 0.f;
  const int* wrow = qw + (size_t)n * (K_DIM / 2);
  for (int g = 0; g < NGROUP; ++g) {
    float s = sc[n * NGROUP + g];
    float z = zp[n * NGROUP + g];
    float partial = 0.f;
    for (int p = 0; p < 64; ++p) {
      int q = wrow[g * 64 + p];
      partial += xs[g * 128 + 2 * p]     * ((float)(q & 15) - z);
      partial += xs[g * 128 + 2 * p + 1] * ((float)((q >> 4) & 15) - z);
    }
    acc = fmaf(partial, s, acc);
  }
  out[(size_t)m * N_DIM + n] = acc;
}

extern "C" void kernel_launch(void* const* d_in, const int* in_sizes, int n_in,
                              void* d_out, int out_size, void* d_ws, size_t ws_size,
                              hipStream_t stream) {
  const float* x  = (const float*)d_in[0];
  const int*   qw = (const int*)d_in[1];
  const float* sc = (const float*)d_in[2];
  const float* zp = (const float*)d_in[3];
  float* out = (float*)d_out;

  const size_t xb_bytes = (size_t)M_DIM * K_DIM * 2;
  const size_t wb_bytes = (size_t)N_DIM * K_DIM * 2;

  if (ws_size >= xb_bytes + wb_bytes) {
    unsigned short* xb = (unsigned short*)d_ws;
    unsigned short* wb = (unsigned short*)((char*)d_ws + xb_bytes);
    cvt_x_kernel<<<dim3((unsigned)((size_t)M_DIM * K_DIM / (256 * 8))), 256, 0, stream>>>(x, xb);
    dequant_kernel<<<dim3((unsigned)((size_t)N_DIM * (K_DIM / 2) / 4 / 256)), 256, 0, stream>>>(qw, sc, zp, wb);
    dim3 grid((M_DIM / BM) * (N_DIM / BN));  // 32*86 = 2752 = 8*344
    gemm_8phase_kernel<<<grid, dim3(512), 98304, stream>>>(xb, wb, out);
  } else {
    dim3 grid(N_DIM / 256, M_DIM);
    fallback_kernel<<<grid, 256, 0, stream>>>(x, qw, sc, zp, out);
  }
}

// Round 8
// 778.727 us; speedup vs baseline: 1.1041x; 1.1041x over previous
//
#include <hip/hip_runtime.h>
#include <hip/hip_bf16.h>
#include <stdint.h>

// Problem constants: B=4, S=2048, IN=4096, OUT=11008
#define M_DIM 8192   // B*S
#define N_DIM 11008  // OUT
#define K_DIM 4096   // IN
#define NGROUP 32    // K_DIM/128

#define BM 256
#define BN 256
#define BK 64
#define NT (K_DIM / BK)  // 64 K-tiles

typedef __attribute__((ext_vector_type(4))) float f32x4;
typedef __attribute__((ext_vector_type(8))) short short8;
typedef __attribute__((ext_vector_type(8))) __bf16 bf16x8;

static_assert(M_DIM % BM == 0 && N_DIM % BN == 0 && K_DIM % BK == 0, "tiling");

__device__ __forceinline__ unsigned short f2bf(float f) {
  union { float f; unsigned int u; } v; v.f = f;
  unsigned int r = v.u + 0x7FFFu + ((v.u >> 16) & 1u);  // RNE
  return (unsigned short)(r >> 16);
}

// ---------- prepass 1: x fp32 -> bf16 ----------
__global__ __launch_bounds__(256) void cvt_x_kernel(const float* __restrict__ x,
                                                    unsigned short* __restrict__ xb) {
  size_t i = ((size_t)blockIdx.x * 256 + threadIdx.x) * 8;
  float4 a = *(const float4*)(x + i);
  float4 b = *(const float4*)(x + i + 4);
  short8 o;
  o[0] = (short)f2bf(a.x); o[1] = (short)f2bf(a.y);
  o[2] = (short)f2bf(a.z); o[3] = (short)f2bf(a.w);
  o[4] = (short)f2bf(b.x); o[5] = (short)f2bf(b.y);
  o[6] = (short)f2bf(b.z); o[7] = (short)f2bf(b.w);
  *(short8*)(xb + i) = o;
}

// ---------- prepass 2: dequant packed int4 -> bf16 W[N][K] ----------
__global__ __launch_bounds__(256) void dequant_kernel(const int* __restrict__ qw,
                                                      const float* __restrict__ sc,
                                                      const float* __restrict__ zp,
                                                      unsigned short* __restrict__ W) {
  size_t chunk = (size_t)blockIdx.x * 256 + threadIdx.x;  // 4 packed int32 = 8 weights
  int row = (int)(chunk >> 9);
  int c4  = (int)(chunk & 511);
  int g   = c4 >> 4;
  float s = sc[row * NGROUP + g];
  float z = zp[row * NGROUP + g];
  int4 q = *(const int4*)(qw + (size_t)row * 2048 + c4 * 4);
  int qq[4] = {q.x, q.y, q.z, q.w};
  short8 o;
#pragma unroll
  for (int t = 0; t < 4; ++t) {
    o[2 * t]     = (short)f2bf(((float)(qq[t] & 15)        - z) * s);
    o[2 * t + 1] = (short)f2bf(((float)((qq[t] >> 4) & 15) - z) * s);
  }
  *(short8*)(W + (size_t)row * K_DIM + (size_t)c4 * 8) = o;
}

// ---------- 256x256 GEMM, R5 phases, minimal barriers (2/K-tile) ----------
__device__ __forceinline__ void gload_lds16(const void* g, void* l) {
  __builtin_amdgcn_global_load_lds((__attribute__((address_space(1))) void*)g,
                                   (__attribute__((address_space(3))) void*)l,
                                   16, 0, 0);
}

// Stage one k-half panel [256 rows][32 cols] (16KB), 2 gload_lds per thread.
__device__ __forceinline__ void stage2(const unsigned short* s0,
                                       const unsigned short* s1,
                                       unsigned short* panel, int wave, int koff) {
  gload_lds16(s0 + koff, panel + wave * 512);
  gload_lds16(s1 + koff, panel + 4096 + wave * 512);
}

#define VMC(N) asm volatile("s_waitcnt vmcnt(" #N ")" ::: "memory")
#define PUB(N) { VMC(N); __builtin_amdgcn_s_barrier(); }   // publish point

// Phase reading BOTH av (per m-half) and bv (reused across m-halves of this k-half).
// SYNC_STMT: either PUB(n) or empty (lockstep barrier removed).
#define PHASE_RB(PA, PB, MH, STAGE_STMT, SYNC_STMT)                                 \
  {                                                                                 \
    bf16x8 av[4];                                                                   \
    _Pragma("unroll") for (int m_ = 0; m_ < 4; ++m_)                                \
      av[m_] = *(const bf16x8*)&(PA)[abase + ((MH)*4 + m_) * 512];                  \
    _Pragma("unroll") for (int n_ = 0; n_ < 4; ++n_)                                \
      bv[n_] = *(const bf16x8*)&(PB)[bbase + n_ * 512];                             \
    STAGE_STMT;                                                                     \
    __builtin_amdgcn_s_setprio(1);                                                  \
    _Pragma("unroll") for (int m_ = 0; m_ < 4; ++m_)                                \
      _Pragma("unroll") for (int n_ = 0; n_ < 4; ++n_)                              \
        acc[(MH)*4 + m_][n_] =                                                      \
            __builtin_amdgcn_mfma_f32_16x16x32_bf16(av[m_], bv[n_],                 \
                                                    acc[(MH)*4 + m_][n_], 0, 0, 0); \
    __builtin_amdgcn_s_setprio(0);                                                  \
    SYNC_STMT;                                                                      \
  }

// Phase reusing bv from the previous phase (same k-half), reads only av.
#define PHASE_NB(PA, MH, STAGE_STMT, SYNC_STMT)                                     \
  {                                                                                 \
    bf16x8 av[4];                                                                   \
    _Pragma("unroll") for (int m_ = 0; m_ < 4; ++m_)                                \
      av[m_] = *(const bf16x8*)&(PA)[abase + ((MH)*4 + m_) * 512];                  \
    STAGE_STMT;                                                                     \
    __builtin_amdgcn_s_setprio(1);                                                  \
    _Pragma("unroll") for (int m_ = 0; m_ < 4; ++m_)                                \
      _Pragma("unroll") for (int n_ = 0; n_ < 4; ++n_)                              \
        acc[(MH)*4 + m_][n_] =                                                      \
            __builtin_amdgcn_mfma_f32_16x16x32_bf16(av[m_], bv[n_],                 \
                                                    acc[(MH)*4 + m_][n_], 0, 0, 0); \
    __builtin_amdgcn_s_setprio(0);                                                  \
    SYNC_STMT;                                                                      \
  }

__global__ __launch_bounds__(512, 2) void gemm_8phase_kernel(const unsigned short* __restrict__ A,
                                                             const unsigned short* __restrict__ B,
                                                             float* __restrict__ C) {
  extern __shared__ unsigned short lds[];
  unsigned short* As = lds;            // [2 buf][2 kh][256*32]  = 64KB
  unsigned short* Bs = lds + 32768;    // same                   = 64KB

  const int tid  = threadIdx.x;
  const int wave = tid >> 6;
  const int lane = tid & 63;
  const int wm = wave >> 2;   // 0..1 -> 128-row slab
  const int wn = wave & 3;    // 0..3 -> 64-col slab
  const int fr = lane & 15;
  const int cp = (lane >> 4) ^ ((fr >> 1) & 3);  // swizzled physical 16B-block (0-conflict)

  // XCD-chunked block swizzle (1376 = 8*172, bijective), bm-major mapping
  const int wg  = blockIdx.x;
  const int sz_ = (wg & 7) * 172 + (wg >> 3);
  const int bm = sz_ / 43;
  const int bn = sz_ % 43;
  const size_t row0 = (size_t)bm * BM;
  const size_t col0 = (size_t)bn * BN;

  const unsigned short* Ab = A + row0 * K_DIM;
  const unsigned short* Bb = B + col0 * K_DIM;

  // precomputed per-lane staging sources (swizzle baked into global col, rule #21)
  const int cl = (tid & 3) ^ ((tid >> 3) & 3);
  const int r0 = tid >> 2;
  const unsigned short* asrc0 = Ab + (size_t)r0 * K_DIM + cl * 8;
  const unsigned short* asrc1 = Ab + (size_t)(r0 + 128) * K_DIM + cl * 8;
  const unsigned short* bsrc0 = Bb + (size_t)r0 * K_DIM + cl * 8;
  const unsigned short* bsrc1 = Bb + (size_t)(r0 + 128) * K_DIM + cl * 8;

  // fragment LDS element offsets (panel-local); frag mi at abase + mi*512
  const int abase = (wm * 128 + fr) * 32 + cp * 8;
  const int bbase = (wn * 64 + fr) * 32 + cp * 8;

  f32x4 acc[8][4];
#pragma unroll
  for (int i = 0; i < 8; ++i)
#pragma unroll
    for (int j = 0; j < 4; ++j) acc[i][j] = (f32x4){0.f, 0.f, 0.f, 0.f};

  bf16x8 bv[4];  // hoisted B fragments, live across one k-half (2 phases)

  // ---- prologue: stage tile 0 fully (kh0 group, kh1 group) ----
  stage2(asrc0, asrc1, As + 0 * 8192, wave, 0);
  stage2(bsrc0, bsrc1, Bs + 0 * 8192, wave, 0);
  stage2(asrc0, asrc1, As + 1 * 8192, wave, 32);
  stage2(bsrc0, bsrc1, Bs + 1 * 8192, wave, 32);
  PUB(4);                       // kh0 published; kh1 may be in flight

  // ---- main loop: 4 phases per K-tile, barriers ONLY at the two publish points ----
  for (int T = 0; T < NT - 1; ++T) {
    const int buf = T & 1, nb = buf ^ 1;
    unsigned short* A0 = As + (buf * 2 + 0) * 8192;
    unsigned short* A1 = As + (buf * 2 + 1) * 8192;
    unsigned short* B0 = Bs + (buf * 2 + 0) * 8192;
    unsigned short* B1 = Bs + (buf * 2 + 1) * 8192;
    unsigned short* nA0 = As + (nb * 2 + 0) * 8192;
    unsigned short* nA1 = As + (nb * 2 + 1) * 8192;
    unsigned short* nB0 = Bs + (nb * 2 + 0) * 8192;
    unsigned short* nB1 = Bs + (nb * 2 + 1) * 8192;
    const int k0 = (T + 1) * 64;      // prefetch col offset (elems)

    // ph1: (k0, mh0) reads av+bv, stage (T+1).Ak0          [no barrier]
    PHASE_RB(A0, B0, 0, stage2(asrc0, asrc1, nA0, wave, k0), );
    // ph2: (k0, mh1) reuses bv, stage (T+1).Bk0; PUBLISH T.kh1 (retires T-1 ph3/ph4 loads)
    PHASE_NB(A0, 1, stage2(bsrc0, bsrc1, nB0, wave, k0), PUB(4));
    // ph3: (k1, mh0) reads av+bv, stage (T+1).Ak1          [no barrier]
    PHASE_RB(A1, B1, 0, stage2(asrc0, asrc1, nA1, wave, k0 + 32), );
    // ph4: (k1, mh1) reuses bv, stage (T+1).Bk1; PUBLISH (T+1).kh0 (retires T ph1/ph2 loads)
    PHASE_NB(A1, 1, stage2(bsrc0, bsrc1, nB1, wave, k0 + 32), PUB(4));
  }
  // ---- last tile: no prefetch; publish kh1 before ph3 ----
  {
    const int buf = (NT - 1) & 1;
    unsigned short* A0 = As + (buf * 2 + 0) * 8192;
    unsigned short* A1 = As + (buf * 2 + 1) * 8192;
    unsigned short* B0 = Bs + (buf * 2 + 0) * 8192;
    unsigned short* B1 = Bs + (buf * 2 + 1) * 8192;
    PHASE_RB(A0, B0, 0, , );
    PHASE_NB(A0, 1, , PUB(0));
    PHASE_RB(A1, B1, 0, , );
    PHASE_NB(A1, 1, , );
  }

  // ---- epilogue: C/D layout col = lane&15, row = (lane>>4)*4 + v ----
  const int orow = (lane >> 4) * 4;
#pragma unroll
  for (int mi = 0; mi < 8; ++mi) {
#pragma unroll
    for (int n = 0; n < 4; ++n) {
      const size_t r = row0 + wm * 128 + mi * 16 + orow;
      const size_t c = col0 + wn * 64 + n * 16 + fr;
#pragma unroll
      for (int v = 0; v < 4; ++v)
        C[(r + v) * N_DIM + c] = acc[mi][n][v];
    }
  }
}

// ---------- fallback (only if d_ws too small): naive fused ----------
__global__ __launch_bounds__(256) void fallback_kernel(const float* __restrict__ x,
                                                       const int* __restrict__ qw,
                                                       const float* __restrict__ sc,
                                                       const float* __restrict__ zp,
                                                       float* __restrict__ out) {
  __shared__ float xs[K_DIM];
  const int m = blockIdx.y;
  const int n = blockIdx.x * 256 + threadIdx.x;
  for (int i = threadIdx.x; i < K_DIM; i += 256) xs[i] = x[(size_t)m * K_DIM + i];
  __syncthreads();
  float acc = 0.f;
  const int* wrow = qw + (size_t)n * (K_DIM / 2);
  for (int g = 0; g < NGROUP; ++g) {
    float s = sc[n * NGROUP + g];
    float z = zp[n * NGROUP + g];
    float partial = 0.f;
    for (int p = 0; p < 64; ++p) {
      int q = wrow[g * 64 + p];
      partial += xs[g * 128 + 2 * p]     * ((float)(q & 15) - z);
      partial += xs[g * 128 + 2 * p + 1] * ((float)((q >> 4) & 15) - z);
    }
    acc = fmaf(partial, s, acc);
  }
  out[(size_t)m * N_DIM + n] = acc;
}

extern "C" void kernel_launch(void* const* d_in, const int* in_sizes, int n_in,
                              void* d_out, int out_size, void* d_ws, size_t ws_size,
                              hipStream_t stream) {
  const float* x  = (const float*)d_in[0];
  const int*   qw = (const int*)d_in[1];
  const float* sc = (const float*)d_in[2];
  const float* zp = (const float*)d_in[3];
  float* out = (float*)d_out;

  const size_t xb_bytes = (size_t)M_DIM * K_DIM * 2;
  const size_t wb_bytes = (size_t)N_DIM * K_DIM * 2;

  if (ws_size >= xb_bytes + wb_bytes) {
    unsigned short* xb = (unsigned short*)d_ws;
    unsigned short* wb = (unsigned short*)((char*)d_ws + xb_bytes);
    cvt_x_kernel<<<dim3((unsigned)((size_t)M_DIM * K_DIM / (256 * 8))), 256, 0, stream>>>(x, xb);
    dequant_kernel<<<dim3((unsigned)((size_t)N_DIM * (K_DIM / 2) / 4 / 256)), 256, 0, stream>>>(qw, sc, zp, wb);
    dim3 grid((M_DIM / BM) * (N_DIM / BN));  // 32*43 = 1376
    gemm_8phase_kernel<<<grid, dim3(512), 131072, stream>>>(xb, wb, out);
  } else {
    dim3 grid(N_DIM / 256, M_DIM);
    fallback_kernel<<<grid, 256, 0, stream>>>(x, qw, sc, zp, out);
  }
}

// Round 9
// 765.631 us; speedup vs baseline: 1.1230x; 1.0171x over previous
//
#include <hip/hip_runtime.h>
#include <hip/hip_bf16.h>
#include <stdint.h>

// Problem constants: B=4, S=2048, IN=4096, OUT=11008
#define M_DIM 8192   // B*S
#define N_DIM 11008  // OUT
#define K_DIM 4096   // IN
#define NGROUP 32    // K_DIM/128

#define BM 256
#define BN 256
#define BK 64
#define NT (K_DIM / BK)  // 64 K-tiles

typedef __attribute__((ext_vector_type(4))) float f32x4;
typedef __attribute__((ext_vector_type(8))) short short8;
typedef __attribute__((ext_vector_type(8))) __bf16 bf16x8;

static_assert(M_DIM % BM == 0 && N_DIM % BN == 0 && K_DIM % BK == 0, "tiling");

__device__ __forceinline__ unsigned short f2bf(float f) {
  union { float f; unsigned int u; } v; v.f = f;
  unsigned int r = v.u + 0x7FFFu + ((v.u >> 16) & 1u);  // RNE
  return (unsigned short)(r >> 16);
}

// ---------- prepass 1: x fp32 -> bf16 ----------
__global__ __launch_bounds__(256) void cvt_x_kernel(const float* __restrict__ x,
                                                    unsigned short* __restrict__ xb) {
  size_t i = ((size_t)blockIdx.x * 256 + threadIdx.x) * 8;
  float4 a = *(const float4*)(x + i);
  float4 b = *(const float4*)(x + i + 4);
  short8 o;
  o[0] = (short)f2bf(a.x); o[1] = (short)f2bf(a.y);
  o[2] = (short)f2bf(a.z); o[3] = (short)f2bf(a.w);
  o[4] = (short)f2bf(b.x); o[5] = (short)f2bf(b.y);
  o[6] = (short)f2bf(b.z); o[7] = (short)f2bf(b.w);
  *(short8*)(xb + i) = o;
}

// ---------- prepass 2: dequant packed int4 -> bf16 W[N][K] ----------
__global__ __launch_bounds__(256) void dequant_kernel(const int* __restrict__ qw,
                                                      const float* __restrict__ sc,
                                                      const float* __restrict__ zp,
                                                      unsigned short* __restrict__ W) {
  size_t chunk = (size_t)blockIdx.x * 256 + threadIdx.x;  // 4 packed int32 = 8 weights
  int row = (int)(chunk >> 9);
  int c4  = (int)(chunk & 511);
  int g   = c4 >> 4;
  float s = sc[row * NGROUP + g];
  float z = zp[row * NGROUP + g];
  int4 q = *(const int4*)(qw + (size_t)row * 2048 + c4 * 4);
  int qq[4] = {q.x, q.y, q.z, q.w};
  short8 o;
#pragma unroll
  for (int t = 0; t < 4; ++t) {
    o[2 * t]     = (short)f2bf(((float)(qq[t] & 15)        - z) * s);
    o[2 * t + 1] = (short)f2bf(((float)((qq[t] >> 4) & 15) - z) * s);
  }
  *(short8*)(W + (size_t)row * K_DIM + (size_t)c4 * 8) = o;
}

// ---------- 256x256 GEMM, register-pipelined fragments, 2 barriers/K-tile ----------
__device__ __forceinline__ void gload_lds16(const void* g, void* l) {
  __builtin_amdgcn_global_load_lds((__attribute__((address_space(1))) void*)g,
                                   (__attribute__((address_space(3))) void*)l,
                                   16, 0, 0);
}

// Stage one k-half panel [256 rows][32 cols] (16KB), 2 gload_lds per thread.
__device__ __forceinline__ void stage2(const unsigned short* s0,
                                       const unsigned short* s1,
                                       unsigned short* panel, int wave, int koff) {
  gload_lds16(s0 + koff, panel + wave * 512);
  gload_lds16(s1 + koff, panel + 4096 + wave * 512);
}

#define VMC(N) asm volatile("s_waitcnt vmcnt(" #N ")" ::: "memory")
#define PUB(N) { VMC(N); __builtin_amdgcn_s_barrier(); }   // publish point

// Issue next-phase fragment reads (pure ds_read; results used next phase).
#define RD_AV(DST, P, MH)                                                    \
  _Pragma("unroll") for (int m_ = 0; m_ < 4; ++m_)                           \
    DST[m_] = *(const bf16x8*)&(P)[abase + ((MH)*4 + m_) * 512];
#define RD_BV(DST, P)                                                        \
  _Pragma("unroll") for (int n_ = 0; n_ < 4; ++n_)                           \
    DST[n_] = *(const bf16x8*)&(P)[bbase + n_ * 512];

// MFMA cluster on registers loaded one phase earlier.
#define MFMA_BLK(MH, AV, BV)                                                 \
  {                                                                          \
    __builtin_amdgcn_s_setprio(1);                                           \
    _Pragma("unroll") for (int m_ = 0; m_ < 4; ++m_)                         \
      _Pragma("unroll") for (int n_ = 0; n_ < 4; ++n_)                       \
        acc[(MH)*4 + m_][n_] = __builtin_amdgcn_mfma_f32_16x16x32_bf16(      \
            AV[m_], BV[n_], acc[(MH)*4 + m_][n_], 0, 0, 0);                  \
    __builtin_amdgcn_s_setprio(0);                                           \
  }

__global__ __launch_bounds__(512, 2) void gemm_8phase_kernel(const unsigned short* __restrict__ A,
                                                             const unsigned short* __restrict__ B,
                                                             float* __restrict__ C) {
  extern __shared__ unsigned short lds[];
  unsigned short* As = lds;            // [2 buf][2 kh][256*32]  = 64KB
  unsigned short* Bs = lds + 32768;    // same                   = 64KB

  const int tid  = threadIdx.x;
  const int wave = tid >> 6;
  const int lane = tid & 63;
  const int wm = wave >> 2;   // 0..1 -> 128-row slab
  const int wn = wave & 3;    // 0..3 -> 64-col slab
  const int fr = lane & 15;
  const int cp = (lane >> 4) ^ ((fr >> 1) & 3);  // swizzled physical 16B-block (0-conflict)

  // XCD-chunked block swizzle (1376 = 8*172, bijective), bm-major mapping
  const int wg  = blockIdx.x;
  const int sz_ = (wg & 7) * 172 + (wg >> 3);
  const int bm = sz_ / 43;
  const int bn = sz_ % 43;
  const size_t row0 = (size_t)bm * BM;
  const size_t col0 = (size_t)bn * BN;

  const unsigned short* Ab = A + row0 * K_DIM;
  const unsigned short* Bb = B + col0 * K_DIM;

  // precomputed per-lane staging sources (swizzle baked into global col, rule #21)
  const int cl = (tid & 3) ^ ((tid >> 3) & 3);
  const int r0 = tid >> 2;
  const unsigned short* asrc0 = Ab + (size_t)r0 * K_DIM + cl * 8;
  const unsigned short* asrc1 = Ab + (size_t)(r0 + 128) * K_DIM + cl * 8;
  const unsigned short* bsrc0 = Bb + (size_t)r0 * K_DIM + cl * 8;
  const unsigned short* bsrc1 = Bb + (size_t)(r0 + 128) * K_DIM + cl * 8;

  // fragment LDS element offsets (panel-local); frag mi at abase + mi*512
  const int abase = (wm * 128 + fr) * 32 + cp * 8;
  const int bbase = (wn * 64 + fr) * 32 + cp * 8;

  f32x4 acc[8][4];
#pragma unroll
  for (int i = 0; i < 8; ++i)
#pragma unroll
    for (int j = 0; j < 4; ++j) acc[i][j] = (f32x4){0.f, 0.f, 0.f, 0.f};

  // ping-pong fragment register sets (even phases use set0, odd use set1)
  bf16x8 av0[4], av1[4], bv0[4], bv1[4];

  // ---- prologue: stage tile 0 fully; pre-read P1's fragments ----
  stage2(asrc0, asrc1, As + 0 * 8192, wave, 0);
  stage2(bsrc0, bsrc1, Bs + 0 * 8192, wave, 0);
  stage2(asrc0, asrc1, As + 1 * 8192, wave, 32);
  stage2(bsrc0, bsrc1, Bs + 1 * 8192, wave, 32);
  VMC(4);                       // A0,B0 landed; A1,B1 may be in flight
  __builtin_amdgcn_s_barrier();
  RD_AV(av0, As + 0 * 8192, 0);
  RD_BV(bv0, Bs + 0 * 8192);

  // ---- main loop: 4 phases/K-tile; each phase pre-reads the NEXT phase's frags ----
  for (int T = 0; T < NT - 1; ++T) {
    const int buf = T & 1, nb = buf ^ 1;
    unsigned short* A0 = As + (buf * 2 + 0) * 8192;
    unsigned short* A1 = As + (buf * 2 + 1) * 8192;
    unsigned short* B0 = Bs + (buf * 2 + 0) * 8192;
    unsigned short* B1 = Bs + (buf * 2 + 1) * 8192;
    unsigned short* nA0 = As + (nb * 2 + 0) * 8192;
    unsigned short* nA1 = As + (nb * 2 + 1) * 8192;
    unsigned short* nB0 = Bs + (nb * 2 + 0) * 8192;
    unsigned short* nB1 = Bs + (nb * 2 + 1) * 8192;
    const int k0 = (T + 1) * 64;      // prefetch col offset (elems)

    // P1: MFMA(k0,mh0) on {av0,bv0}; pre-read av1<-A0.mh1; stage nA0;
    //     PUBLISH kh1 (VMC(2): retires A1,B1; leaves nA0 in flight)
    RD_AV(av1, A0, 1);
    stage2(asrc0, asrc1, nA0, wave, k0);
    MFMA_BLK(0, av0, bv0);
    PUB(2);
    // P2: MFMA(k0,mh1) on {av1,bv0}; pre-read av0<-A1.mh0, bv1<-B1; stage nB0
    RD_AV(av0, A1, 0);
    RD_BV(bv1, B1);
    stage2(bsrc0, bsrc1, nB0, wave, k0);
    MFMA_BLK(1, av1, bv0);
    // P3: MFMA(k1,mh0) on {av0,bv1}; pre-read av1<-A1.mh1; stage nA1;
    //     PUBLISH next kh0 (VMC(2): retires nA0,nB0; leaves nA1 in flight)
    RD_AV(av1, A1, 1);
    stage2(asrc0, asrc1, nA1, wave, k0 + 32);
    MFMA_BLK(0, av0, bv1);
    PUB(2);
    // P4: MFMA(k1,mh1) on {av1,bv1}; pre-read av0<-nA0.mh0, bv0<-nB0 (next tile P1); stage nB1
    RD_AV(av0, nA0, 0);
    RD_BV(bv0, nB0);
    stage2(bsrc0, bsrc1, nB1, wave, k0 + 32);
    MFMA_BLK(1, av1, bv1);
  }
  // ---- last tile: no staging; drain kh1 then finish ----
  {
    const int buf = (NT - 1) & 1;
    unsigned short* A0 = As + (buf * 2 + 0) * 8192;
    unsigned short* A1 = As + (buf * 2 + 1) * 8192;
    unsigned short* B1 = Bs + (buf * 2 + 1) * 8192;
    // P1
    RD_AV(av1, A0, 1);
    MFMA_BLK(0, av0, bv0);
    PUB(0);                      // retires nA1,nB1 -> A1,B1 readable
    // P2
    RD_AV(av0, A1, 0);
    RD_BV(bv1, B1);
    MFMA_BLK(1, av1, bv0);
    // P3
    RD_AV(av1, A1, 1);
    MFMA_BLK(0, av0, bv1);
    // P4
    MFMA_BLK(1, av1, bv1);
  }

  // ---- epilogue: C/D layout col = lane&15, row = (lane>>4)*4 + v ----
  const int orow = (lane >> 4) * 4;
#pragma unroll
  for (int mi = 0; mi < 8; ++mi) {
#pragma unroll
    for (int n = 0; n < 4; ++n) {
      const size_t r = row0 + wm * 128 + mi * 16 + orow;
      const size_t c = col0 + wn * 64 + n * 16 + fr;
#pragma unroll
      for (int v = 0; v < 4; ++v)
        C[(r + v) * N_DIM + c] = acc[mi][n][v];
    }
  }
}

// ---------- fallback (only if d_ws too small): naive fused ----------
__global__ __launch_bounds__(256) void fallback_kernel(const float* __restrict__ x,
                                                       const int* __restrict__ qw,
                                                       const float* __restrict__ sc,
                                                       const float* __restrict__ zp,
                                                       float* __restrict__ out) {
  __shared__ float xs[K_DIM];
  const int m = blockIdx.y;
  const int n = blockIdx.x * 256 + threadIdx.x;
  for (int i = threadIdx.x; i < K_DIM; i += 256) xs[i] = x[(size_t)m * K_DIM + i];
  __syncthreads();
  float acc = 0.f;
  const int* wrow = qw + (size_t)n * (K_DIM / 2);
  for (int g = 0; g < NGROUP; ++g) {
    float s = sc[n * NGROUP + g];
    float z = zp[n * NGROUP + g];
    float partial = 0.f;
    for (int p = 0; p < 64; ++p) {
      int q = wrow[g * 64 + p];
      partial += xs[g * 128 + 2 * p]     * ((float)(q & 15) - z);
      partial += xs[g * 128 + 2 * p + 1] * ((float)((q >> 4) & 15) - z);
    }
    acc = fmaf(partial, s, acc);
  }
  out[(size_t)m * N_DIM + n] = acc;
}

extern "C" void kernel_launch(void* const* d_in, const int* in_sizes, int n_in,
                              void* d_out, int out_size, void* d_ws, size_t ws_size,
                              hipStream_t stream) {
  const float* x  = (const float*)d_in[0];
  const int*   qw = (const int*)d_in[1];
  const float* sc = (const float*)d_in[2];
  const float* zp = (const float*)d_in[3];
  float* out = (float*)d_out;

  const size_t xb_bytes = (size_t)M_DIM * K_DIM * 2;
  const size_t wb_bytes = (size_t)N_DIM * K_DIM * 2;

  if (ws_size >= xb_bytes + wb_bytes) {
    unsigned short* xb = (unsigned short*)d_ws;
    unsigned short* wb = (unsigned short*)((char*)d_ws + xb_bytes);
    cvt_x_kernel<<<dim3((unsigned)((size_t)M_DIM * K_DIM / (256 * 8))), 256, 0, stream>>>(x, xb);
    dequant_kernel<<<dim3((unsigned)((size_t)N_DIM * (K_DIM / 2) / 4 / 256)), 256, 0, stream>>>(qw, sc, zp, wb);
    dim3 grid((M_DIM / BM) * (N_DIM / BN));  // 32*43 = 1376
    gemm_8phase_kernel<<<grid, dim3(512), 131072, stream>>>(xb, wb, out);
  } else {
    dim3 grid(N_DIM / 256, M_DIM);
    fallback_kernel<<<grid, 256, 0, stream>>>(x, qw, sc, zp, out);
  }
}